// Round 9
// baseline (28965.079 us; speedup 1.0000x reference)
//
#include <hip/hip_runtime.h>
#include <cstdint>
#include <cstddef>

using u16 = unsigned short;
using u32 = unsigned int;

typedef __attribute__((ext_vector_type(8))) __bf16 bf16x8;
typedef __attribute__((ext_vector_type(8))) short short8;
typedef __attribute__((ext_vector_type(4))) float f32x4;

__device__ __forceinline__ float bf2f(u16 u){
  union { u32 i; float f; } v; v.i = ((u32)u) << 16; return v.f;
}
__device__ __forceinline__ u16 f2bf(float f){
  union { float f; u32 i; } v; v.f = f;
  return (u16)((v.i + 0x7FFFu + ((v.i >> 16) & 1u)) >> 16);
}
__device__ __forceinline__ float sigm(float x){ return 1.0f / (1.0f + __expf(-x)); }
__device__ __forceinline__ f32x4 mfma16(bf16x8 a, bf16x8 b, f32x4 c){
  return __builtin_amdgcn_mfma_f32_16x16x32_bf16(a, b, c, 0, 0, 0);
}
__device__ __forceinline__ float ldin(const void* p, size_t i, bool f){
  return f ? ((const float*)p)[i] : bf2f(((const u16*)p)[i]);
}

// ---- coherence-point (MALL) access primitives: bypass L1/L2 ----
__device__ __forceinline__ uint4 ldx4_cg(const u16* p){
  uint4 r;
  asm volatile("global_load_dwordx4 %0, %1, off sc0 sc1" : "=v"(r) : "v"(p) : "memory");
  return r;
}
__device__ __forceinline__ void st16_cg(u16* p, u32 v){
  asm volatile("global_store_short %0, %1, off sc0 sc1" :: "v"(p), "v"(v) : "memory");
}
__device__ __forceinline__ void wait_vm0(){ asm volatile("s_waitcnt vmcnt(0)" ::: "memory"); }

__device__ __forceinline__ void bar_arrive(u32* bar){
  __hip_atomic_fetch_add(bar, 1u, __ATOMIC_RELAXED, __HIP_MEMORY_SCOPE_AGENT);
}
__device__ __forceinline__ void bar_spin(u32* bar, u32 tgt){
  while (__hip_atomic_load(bar, __ATOMIC_RELAXED, __HIP_MEMORY_SCOPE_AGENT) < tgt)
    __builtin_amdgcn_s_sleep(1);
}

// ---------------- dtype detection ----------------
__global__ __launch_bounds__(256) void k_detect(const u32* __restrict__ embw, u32* __restrict__ dflag){
  int tid = threadIdx.x;
  u32 cnt = 0;
  for (int t = 0; t < 32; ++t){
    u32 w = embw[t*256 + tid];
    u32 e = (w >> 7) & 0xFFu;
    cnt += (e >= 0xC0u) ? 1u : 0u;
  }
  atomicAdd(dflag, cnt);
}

// ---------------- pack (weights -> bf16/f32 in ws) ----------------

__global__ __launch_bounds__(256) void k_pack(
  const void* eWihF, const void* eWihB, const void* ebF, const void* ebB,
  const void* dWih, const void* dWhh, const void* db, const void* Wtag,
  const void* eWhhF, const void* eWhhB, const void* Watt, const void* btag,
  const u32* __restrict__ dflag,
  u16* __restrict__ WihCat, float* __restrict__ bcat, u16* __restrict__ WihH,
  u16* __restrict__ Wf, float* __restrict__ lbv, u16* __restrict__ WtagP,
  u16* __restrict__ WhhFb, u16* __restrict__ WhhBb, u16* __restrict__ Wattb,
  float* __restrict__ btagf)
{
  bool isf = (*dflag > 64u);
  long i = (long)blockIdx.x * 256 + threadIdx.x;
  if (i < 655360){                       // WihCat [2048][320] (K padded 300->320)
    long n = i / 320, e = i - n*320;
    WihCat[i] = (e < 300)
      ? f2bf(ldin(n < 1024 ? eWihF : eWihB, (size_t)(n & 1023)*300 + e, isf)) : (u16)0;
    return;
  }
  i -= 655360;
  if (i < 2048){ bcat[i] = ldin(i < 1024 ? ebF : ebB, (size_t)(i & 1023), isf); return; }
  i -= 2048;
  if (i < 1048576){                      // WihH [2048][512] = dec_Wih[:,512:1024]
    long n = i >> 9, k = i & 511;
    WihH[i] = f2bf(ldin(dWih, (size_t)n*1028 + 512 + k, isf));
    return;
  }
  i -= 1048576;
  if (i < 2097152){                      // Wf: gate weights, A-fragment layout, 8 dim-slices
    long e  = i & 7;
    long ln = (i >> 3) & 63;
    long kt = (i >> 9) & 31;
    long rt = (i >> 14) & 15;
    long w  = (i >> 18) & 7;
    long rl = rt*16 + (ln & 15);         // slice-local row 0..255
    long g2 = rl >> 6, d = rl & 63;
    long n = g2*512 + w*64 + d;          // gate g2, h-dim w*64+d
    long k = kt*32 + (ln >> 4)*8 + e;
    Wf[i] = f2bf((k < 512) ? ldin(dWih, (size_t)n*1028 + k, isf)
                           : ldin(dWhh, (size_t)n*512 + (k - 512), isf));
    return;
  }
  i -= 2097152;
  if (i < 8192){                         // lb [4][2048] = dec_b + onehot col
    long l = i >> 11, n = i & 2047;
    lbv[i] = ldin(db, n, isf) + ldin(dWih, (size_t)n*1028 + 1024 + l, isf);
    return;
  }
  i -= 8192;
  if (i < 8192){                         // WtagP [16][512] padded
    long n = i >> 9, k = i & 511;
    WtagP[i] = (n < 9) ? f2bf(ldin(Wtag, (size_t)n*512 + k, isf)) : (u16)0;
    return;
  }
  i -= 8192;
  if (i < 262144){ WhhFb[i] = f2bf(ldin(eWhhF, i, isf)); return; }
  i -= 262144;
  if (i < 262144){ WhhBb[i] = f2bf(ldin(eWhhB, i, isf)); return; }
  i -= 262144;
  if (i < 262144){ Wattb[i] = f2bf(ldin(Watt, i, isf)); return; }
  i -= 262144;
  if (i < 16){ btagf[i] = (i < 9) ? ldin(btag, i, isf) : 0.f; return; }
}

__global__ __launch_bounds__(256) void k_gather(
  const int* __restrict__ seqs, const void* __restrict__ emb,
  const u32* __restrict__ dflag, u16* __restrict__ X)
{
  bool isf = (*dflag > 64u);
  int idx = blockIdx.x * 256 + threadIdx.x;
  if (idx >= 8192*320) return;
  int row = idx / 320, e = idx - row*320;
  int s = row >> 5, b = row & 31;
  int tok = seqs[b*256 + s];
  X[idx] = (e < 300) ? f2bf(ldin(emb, (size_t)tok*300 + e, isf)) : (u16)0;
}

// ---------------- generic bf16 GEMM: C[M,N] = A[M,K] @ B[N,K]^T (+bias) ----------------

__global__ __launch_bounds__(256) void k_gemm(
  const u16* __restrict__ A, const u16* __restrict__ B, const float* __restrict__ bias,
  u16* __restrict__ C, int M, int N, int K)
{
  int mb = blockIdx.x * 32;
  int wave = threadIdx.x >> 6, lane = threadIdx.x & 63;
  int nb = blockIdx.y * 256 + wave * 64;
  int rlo = lane & 15, klane = (lane >> 4) * 8;
  f32x4 acc[2][4];
  #pragma unroll
  for (int i = 0; i < 2; ++i)
    #pragma unroll
    for (int j = 0; j < 4; ++j) acc[i][j] = (f32x4){0,0,0,0};
  for (int kk = 0; kk < K; kk += 32){
    bf16x8 a0 = *(const bf16x8*)(A + (size_t)(mb + rlo)*K + kk + klane);
    bf16x8 a1 = *(const bf16x8*)(A + (size_t)(mb + 16 + rlo)*K + kk + klane);
    #pragma unroll
    for (int nt = 0; nt < 4; ++nt){
      bf16x8 bv = *(const bf16x8*)(B + (size_t)(nb + nt*16 + rlo)*K + kk + klane);
      acc[0][nt] = mfma16(a0, bv, acc[0][nt]);
      acc[1][nt] = mfma16(a1, bv, acc[1][nt]);
    }
  }
  int rbase = (lane >> 4) * 4;
  #pragma unroll
  for (int mt = 0; mt < 2; ++mt)
    #pragma unroll
    for (int nt = 0; nt < 4; ++nt){
      int col = nb + nt*16 + rlo;
      float badd = bias ? bias[col] : 0.0f;
      #pragma unroll
      for (int r = 0; r < 4; ++r){
        int row = mb + mt*16 + rbase + r;
        C[(size_t)row*N + col] = f2bf(acc[mt][nt][r] + badd);
      }
    }
}

// ---------------- transpose h -> hT[b][d][j] ----------------

__global__ __launch_bounds__(256) void k_transp(const u16* __restrict__ hglob, u16* __restrict__ hT)
{
  __shared__ u16 tile_t[64][264];
  int b = blockIdx.x >> 3, d0 = (blockIdx.x & 7) * 64;
  int t = threadIdx.x;
  for (int rr = 0; rr < 16; ++rr){
    int c = rr*256 + t;
    int j = c >> 4, dq = (c & 15) * 4;
    ushort4 ld = *(const ushort4*)(hglob + ((size_t)(j*32 + b)*512 + d0 + dq));
    tile_t[dq + 0][j] = ld.x;
    tile_t[dq + 1][j] = ld.y;
    tile_t[dq + 2][j] = ld.z;
    tile_t[dq + 3][j] = ld.w;
  }
  __syncthreads();
  for (int rr = 0; rr < 8; ++rr){
    int c = rr*256 + t;
    int d = c >> 5, jq = (c & 31) * 8;
    *(uint4*)(hT + ((size_t)(b*512 + d0 + d)*256 + jq)) = *(const uint4*)&tile_t[d][jq];
  }
}

// ---------------- encoder: persistent, 32 WGs (16 per direction) ----------------

__global__ __launch_bounds__(256, 1) void k_encoder(
  const u16* __restrict__ XW, const u16* __restrict__ WhhF, const u16* __restrict__ WhhB,
  u16* __restrict__ hglob, u16* __restrict__ hstate, u32* ctrlE)
{
  int wg = blockIdx.x;
  int d = wg >> 4, w = wg & 15;
  const u16* Whh = d ? WhhB : WhhF;
  u32* bar = ctrlE + d * 256;          // 1024 B apart
  int tid = threadIdx.x, wave = tid >> 6, lane = tid & 63;
  int cc = lane & 15, q = lane >> 4, klane = q * 8, rbase = q * 4;
  __shared__ __align__(16) u16 hblk[8192];     // [b][256] swizzled
  __shared__ float g_lds[4][32][16];
  __shared__ float c_sh[512];
  c_sh[tid] = 0.f; c_sh[tid + 256] = 0.f;
  __syncthreads();

  for (int t = 0; t < 256; ++t){
    int srow = d ? (255 - t) : t;
    const u16* hr = hstate + (size_t)(d*2 + (t & 1)) * 8192;
    u16*       hw = hstate + (size_t)(d*2 + ((t & 1) ^ 1)) * 8192;

    // stage h block (32 x 256) into LDS
    {
      int c0 = tid, c1 = tid + 256, c2 = tid + 512, c3 = tid + 768;
      uint4 v0 = ldx4_cg(hr + (c0 >> 5)*256 + (c0 & 31)*8);
      uint4 v1 = ldx4_cg(hr + (c1 >> 5)*256 + (c1 & 31)*8);
      uint4 v2 = ldx4_cg(hr + (c2 >> 5)*256 + (c2 & 31)*8);
      uint4 v3 = ldx4_cg(hr + (c3 >> 5)*256 + (c3 & 31)*8);
      wait_vm0();
      *(uint4*)(hblk + (c0 >> 5)*256 + (((c0 & 31) ^ ((c0 >> 5) & 7)))*8) = v0;
      *(uint4*)(hblk + (c1 >> 5)*256 + (((c1 & 31) ^ ((c1 >> 5) & 7)))*8) = v1;
      *(uint4*)(hblk + (c2 >> 5)*256 + (((c2 & 31) ^ ((c2 >> 5) & 7)))*8) = v2;
      *(uint4*)(hblk + (c3 >> 5)*256 + (((c3 & 31) ^ ((c3 >> 5) & 7)))*8) = v3;
    }
    __syncthreads();

    // h @ Whh^T for this WG's 16 cols x 4 gates
    {
      int ncol = wave*256 + w*16 + cc;
      const u16* Brow = Whh + (size_t)ncol*256;
      f32x4 acc0 = {0,0,0,0}, acc1 = {0,0,0,0};
      #pragma unroll
      for (int kt = 0; kt < 8; ++kt){
        bf16x8 bv = *(const bf16x8*)(Brow + kt*32 + klane);
        bf16x8 a0 = *(const bf16x8*)(hblk + cc*256 + ((kt*4 + q) ^ (cc & 7))*8);
        bf16x8 a1 = *(const bf16x8*)(hblk + (cc + 16)*256 + ((kt*4 + q) ^ (cc & 7))*8);
        acc0 = mfma16(a0, bv, acc0);
        acc1 = mfma16(a1, bv, acc1);
      }
      #pragma unroll
      for (int r = 0; r < 4; ++r){
        g_lds[wave][rbase + r][cc]      = acc0[r];
        g_lds[wave][16 + rbase + r][cc] = acc1[r];
      }
    }
    __syncthreads();

    // pointwise
    for (int e = tid; e < 512; e += 256){
      int b_ = e >> 4, jc = e & 15;
      int j = w*16 + jc;
      float pre[4];
      #pragma unroll
      for (int g2 = 0; g2 < 4; ++g2)
        pre[g2] = g_lds[g2][b_][jc] + bf2f(XW[(size_t)(srow*32 + b_)*2048 + d*1024 + g2*256 + j]);
      float iv = sigm(pre[0]), fv = sigm(pre[1]);
      float gv = tanhf(pre[2]), ov = sigm(pre[3]);
      float cv = fv * c_sh[e] + iv * gv;
      c_sh[e] = cv;
      u16 hb = f2bf(ov * tanhf(cv));
      st16_cg(hw + b_*256 + j, (u32)hb);
      __builtin_nontemporal_store(hb, hglob + (size_t)(srow*32 + b_)*512 + d*256 + j);
    }
    wait_vm0();
    __syncthreads();
    if (tid == 0){
      bar_arrive(bar);
      bar_spin(bar, (u32)(t + 1) * 16u);
    }
    __syncthreads();
  }
}

// ---------------- decoder: 4 independent groups of 8 WGs x 8 batches ----------------
// WG (grp, w): attention for batch grp*8+w (Wh VGPR-pinned, hT L2) + gate slice of
// 4 gates x h-dims [w*64, w*64+64) for the group's 8 batches (Wf slice 512KB, L2).
// Exchange (s, ctx) 8KB via MALL; 2x 8-WG barriers/step on group-private lines.

__global__ __launch_bounds__(512, 1) void k_decoder(
  const u16* __restrict__ Whb, const u16* __restrict__ hT,
  const u16* __restrict__ Wf, const u16* __restrict__ Xh, const float* __restrict__ lbv,
  u16* __restrict__ Ain,          // [2][32][1024] bf16: [b][0:512)=ctx, [512:1024)=s
  u16* __restrict__ aouts,        // [32768][512] bf16
  u32* barD)
{
  __shared__ __align__(16) u16 ablk[8*1024];    // [8][1024] 16B-chunk XOR-swizzled
  __shared__ float score_lds[256];
  __shared__ __align__(16) u16 att_bf[256];
  __shared__ float gbuf[256][9];
  __shared__ float c_lds[512];
  const int wg = blockIdx.x, tid = threadIdx.x;
  const int grp = wg >> 3, w = wg & 7;
  const int wave = tid >> 6, lane = tid & 63;
  const int q = lane >> 4, cc = lane & 15;
  u32* bar2 = barD + grp*128;          // ctx barrier (own line)
  u32* bar1 = barD + grp*128 + 64;     // state barrier (own line)
  c_lds[tid] = 0.0f;

  // pin Wh A-fragments for own batch (= wg): wave holds rows [wave*32, wave*32+32)
  bf16x8 wh[2][16];
  #pragma unroll
  for (int rt = 0; rt < 2; ++rt)
    #pragma unroll
    for (int kt = 0; kt < 16; ++kt){
      int row = wave*32 + rt*16 + cc;
      wh[rt][kt] = *(const bf16x8*)(Whb + ((size_t)(row*32 + wg))*512 + kt*32 + q*8);
    }
  const u16* WfW = Wf + (size_t)w*262144;       // slice: 256 rows x 1024 K, frag layout
  const int rt0 = wave*2, rt1 = wave*2 + 1;
  const int pb_ = tid >> 6, pdd = tid & 63;     // pointwise: batch-local, dim-local
  float lb[4];
  __syncthreads();

  for (int iter = 0; iter < 1024; ++iter){
    const int l = iter >> 8, t = iter & 255;
    const u32 e = (u32)(iter + 1);
    u16* AinC = Ain + (iter & 1)*32768;
    u16* AinN = Ain + ((iter & 1) ^ 1)*32768;

    // stage s-block (8 x 512) from MALL -> ablk s-half
    {
      int row = tid >> 6, ch = tid & 63;
      uint4 v = ldx4_cg(AinC + (size_t)(grp*8 + row)*1024 + 512 + ch*8);
      wait_vm0();
      *(uint4*)(ablk + row*1024 + 512 + ((ch ^ (row & 7)))*8) = v;
    }
    __syncthreads();

    // prefetch pointwise operands (cached loads, consumed end of iter)
    if ((iter & 255) == 0){
      #pragma unroll
      for (int g = 0; g < 4; ++g) lb[g] = lbv[l*2048 + g*512 + w*64 + pdd];
    }
    float xh[4];
    #pragma unroll
    for (int g = 0; g < 4; ++g)
      xh[g] = bf2f(Xh[(size_t)(t*32 + grp*8 + pb_)*2048 + g*512 + w*64 + pdd]);

    // scores: MFMA(Wh-VGPR, own-s broadcast)
    f32x4 sa0 = {0,0,0,0}, sa1 = {0,0,0,0};
    #pragma unroll
    for (int kt = 0; kt < 16; ++kt){
      bf16x8 sv = *(const bf16x8*)(ablk + w*1024 + 512 + (((kt*4 + q) ^ (w & 7)))*8);
      sa0 = mfma16(wh[0][kt], sv, sa0);
      sa1 = mfma16(wh[1][kt], sv, sa1);
    }
    if (cc == 0){
      #pragma unroll
      for (int r = 0; r < 4; ++r){
        score_lds[wave*32      + q*4 + r] = sa0[r];
        score_lds[wave*32 + 16 + q*4 + r] = sa1[r];
      }
    }
    __syncthreads();

    // softmax (wave 0, 4 scores/lane)
    if (wave == 0){
      float x0 = score_lds[lane*4+0], x1 = score_lds[lane*4+1];
      float x2 = score_lds[lane*4+2], x3 = score_lds[lane*4+3];
      float m = fmaxf(fmaxf(x0,x1), fmaxf(x2,x3));
      #pragma unroll
      for (int off = 32; off >= 1; off >>= 1) m = fmaxf(m, __shfl_xor(m, off));
      float e0 = __expf(x0-m), e1 = __expf(x1-m), e2 = __expf(x2-m), e3 = __expf(x3-m);
      float s = e0+e1+e2+e3;
      #pragma unroll
      for (int off = 32; off >= 1; off >>= 1) s += __shfl_xor(s, off);
      float inv = 1.0f / s;
      att_bf[lane*4+0] = f2bf(e0*inv);
      att_bf[lane*4+1] = f2bf(e1*inv);
      att_bf[lane*4+2] = f2bf(e2*inv);
      att_bf[lane*4+3] = f2bf(e3*inv);
    }
    __syncthreads();

    // ctx: MFMA(att row-0, hT B-frags). wave owns dims [wave*64, wave*64+64)
    f32x4 ca0 = {0,0,0,0}, ca1 = {0,0,0,0}, ca2 = {0,0,0,0}, ca3 = {0,0,0,0};
    #pragma unroll
    for (int jt = 0; jt < 8; ++jt){
      uint4 au = {0,0,0,0};
      if (cc == 0) au = *(const uint4*)(att_bf + jt*32 + q*8);
      bf16x8 af = *(bf16x8*)&au;
      const u16* hb = hT + ((size_t)(wg*512 + wave*64 + cc))*256 + jt*32 + q*8;
      ca0 = mfma16(af, *(const bf16x8*)(hb +  0*256), ca0);
      ca1 = mfma16(af, *(const bf16x8*)(hb + 16*256), ca1);
      ca2 = mfma16(af, *(const bf16x8*)(hb + 32*256), ca2);
      ca3 = mfma16(af, *(const bf16x8*)(hb + 48*256), ca3);
    }
    if (q == 0){
      u16* dst = AinC + (size_t)wg*1024 + wave*64 + cc;
      st16_cg(dst +  0, (u32)f2bf(ca0[0]));
      st16_cg(dst + 16, (u32)f2bf(ca1[0]));
      st16_cg(dst + 32, (u32)f2bf(ca2[0]));
      st16_cg(dst + 48, (u32)f2bf(ca3[0]));
    }
    wait_vm0();
    __syncthreads();                     // all ctx stores of this WG acked at MALL
    if (tid == 0) bar_arrive(bar2);

    // gate s-half (K 512..1023) — overlaps group peers' ctx production
    f32x4 ga0 = {0,0,0,0}, ga1 = {0,0,0,0};
    #pragma unroll
    for (int kt = 16; kt < 32; ++kt){
      bf16x8 bv = (bf16x8)(short8){0,0,0,0,0,0,0,0};
      if (cc < 8)
        bv = *(const bf16x8*)(ablk + cc*1024 + 512 + ((((kt-16)*4 + q) ^ (cc & 7)))*8);
      ga0 = mfma16(*(const bf16x8*)(WfW + (rt0*32 + kt)*512 + lane*8), bv, ga0);
      ga1 = mfma16(*(const bf16x8*)(WfW + (rt1*32 + kt)*512 + lane*8), bv, ga1);
    }
    if (tid == 0) bar_spin(bar2, 8u*e);
    __syncthreads();

    // stage ctx-block (8 x 512) from MALL -> ablk ctx-half
    {
      int row = tid >> 6, ch = tid & 63;
      uint4 v = ldx4_cg(AinC + (size_t)(grp*8 + row)*1024 + ch*8);
      wait_vm0();
      *(uint4*)(ablk + row*1024 + ((ch ^ (row & 7)))*8) = v;
    }
    __syncthreads();

    // gate ctx-half (K 0..511)
    #pragma unroll
    for (int kt = 0; kt < 16; ++kt){
      bf16x8 bv = (bf16x8)(short8){0,0,0,0,0,0,0,0};
      if (cc < 8)
        bv = *(const bf16x8*)(ablk + cc*1024 + (((kt*4 + q) ^ (cc & 7)))*8);
      ga0 = mfma16(*(const bf16x8*)(WfW + (rt0*32 + kt)*512 + lane*8), bv, ga0);
      ga1 = mfma16(*(const bf16x8*)(WfW + (rt1*32 + kt)*512 + lane*8), bv, ga1);
    }
    if (cc < 8){
      #pragma unroll
      for (int r = 0; r < 4; ++r){
        gbuf[rt0*16 + q*4 + r][cc] = ga0[r];
        gbuf[rt1*16 + q*4 + r][cc] = ga1[r];
      }
    }
    __syncthreads();

    // pointwise: thread = (pb_, pdd); WG owns h-dims [w*64, w*64+64), group batches
    {
      float pre[4];
      #pragma unroll
      for (int g = 0; g < 4; ++g)
        pre[g] = gbuf[g*64 + pdd][pb_] + xh[g] + lb[g];
      float iv = sigm(pre[0]), fv = sigm(pre[1]);
      float gv = tanhf(pre[2]), ov = sigm(pre[3]);
      float cv = fv * c_lds[tid] + iv * gv;
      c_lds[tid] = cv;
      u16 hb = f2bf(ov * tanhf(cv));
      st16_cg(AinN + (size_t)(grp*8 + pb_)*1024 + 512 + w*64 + pdd, (u32)hb);
      __builtin_nontemporal_store(hb,
          aouts + (size_t)((l*256 + t)*32 + grp*8 + pb_)*512 + w*64 + pdd);
    }
    wait_vm0();
    __syncthreads();
    if (tid == 0){
      bar_arrive(bar1);
      bar_spin(bar1, 8u*e);
    }
    __syncthreads();
  }
}

// ---------------- tag projection ----------------

__global__ __launch_bounds__(256) void k_tag(
  const u16* __restrict__ aouts, const u16* __restrict__ WtagP, const float* __restrict__ btagf,
  const u32* __restrict__ dflag, void* __restrict__ out)
{
  bool isf = (*dflag > 64u);
  int wave = threadIdx.x >> 6, lane = threadIdx.x & 63;
  int mb = (blockIdx.x * 4 + wave) * 16;
  int cc = lane & 15, klane = (lane >> 4) * 8;
  f32x4 acc = {0,0,0,0};
  const u16* Arow = aouts + (size_t)(mb + cc)*512;
  const u16* Brow = WtagP + cc*512;
  #pragma unroll
  for (int kk = 0; kk < 512; kk += 32){
    bf16x8 av = *(const bf16x8*)(Arow + kk + klane);
    bf16x8 bv = *(const bf16x8*)(Brow + kk + klane);
    acc = mfma16(av, bv, acc);
  }
  int rbase = (lane >> 4) * 4;
  if (cc < 9){
    float bt = btagf[cc];
    #pragma unroll
    for (int r = 0; r < 4; ++r){
      int row = mb + rbase + r;
      float v = acc[r] + bt;
      if (isf) ((float*)out)[(size_t)row*9 + cc] = v;
      else     ((u16*)out)[(size_t)row*9 + cc] = f2bf(v);
    }
  }
}

// ---------------- host ----------------

extern "C" void kernel_launch(void* const* d_in, const int* in_sizes, int n_in,
                              void* d_out, int out_size, void* d_ws, size_t ws_size,
                              hipStream_t stream)
{
  (void)in_sizes; (void)n_in; (void)out_size;
  if (ws_size < 98625536ull) return;

  const int* seqs = (const int*)d_in[0];

  char* ws = (char*)d_ws;
  u32*    dflag  = (u32*)(ws + 0);
  u32*    barD   = (u32*)(ws + 4096);       // 4 groups x (bar2@+0, bar1@+256B), 512B/group
  u32*    ctrlE  = (u32*)(ws + 12288);      // encoder bars: fwd@12288, bwd@13312
  u16*    Ain    = (u16*)(ws + 16384);      // [2][32][1024] bf16 -> end 147456
  u16*    hstate = (u16*)(ws + 147456);     // [4][32][256] -> end 212992
  // memset end = 212992
  u16*    WihCat = (u16*)(ws + 263168);     // [2048][320]
  float*  bcat   = (float*)(ws + 1573888);  // [2048]
  u16*    WihH   = (u16*)(ws + 1582080);    // [2048][512]
  u16*    Wf     = (u16*)(ws + 3679232);    // [8][16][32][64][8] fragment layout (4MB)
  float*  lbv    = (float*)(ws + 7873536);  // [4][2048]
  u16*    WtagP  = (u16*)(ws + 7906304);    // [16][512]
  u16*    WhhFb  = (u16*)(ws + 7922688);    // [1024][256]
  u16*    WhhBb  = (u16*)(ws + 8446976);    // [1024][256]
  u16*    Wattb  = (u16*)(ws + 8971264);    // [512][512]
  float*  btagf  = (float*)(ws + 9495552);  // [16]
  u16*    X      = (u16*)(ws + 9496576);    // [8192][320]
  u16*    XWXh   = (u16*)(ws + 14739456);   // [8192][2048] XW, later Xh (aliased)
  u16*    aouts  = (u16*)(ws + 48293888);   // [32768][512]; first 8.4MB doubles as hglob pre-decoder
  u16*    hglob  = (u16*)(ws + 48293888);   // alias (dead before decoder writes aouts)
  u16*    hT     = (u16*)(ws + 81848320);   // [32][512][256]
  u16*    Whb    = (u16*)(ws + 90236928);   // [8192][512]

  hipMemsetAsync(d_ws, 0, 212992, stream);

  k_detect<<<1, 256, 0, stream>>>((const u32*)d_in[1], dflag);
  k_pack<<<17993, 256, 0, stream>>>(
      d_in[2], d_in[5], d_in[4], d_in[7], d_in[9], d_in[10], d_in[11], d_in[12],
      d_in[3], d_in[6], d_in[8], d_in[13], dflag,
      WihCat, bcat, WihH, Wf, lbv, WtagP, WhhFb, WhhBb, Wattb, btagf);
  k_gather<<<10240, 256, 0, stream>>>(seqs, d_in[1], dflag, X);
  // XW = X @ [Wih_f; Wih_b]^T + bias
  k_gemm<<<dim3(256, 8), 256, 0, stream>>>(X, WihCat, bcat, XWXh, 8192, 2048, 320);
  k_encoder<<<32, 256, 0, stream>>>(XWXh, WhhFb, WhhBb, hglob, hstate, ctrlE);
  // Wh = h @ W_att^T ; Xh = h @ Wih_h^T (aliases XW)
  k_gemm<<<dim3(256, 2), 256, 0, stream>>>(hglob, Wattb, nullptr, Whb, 8192, 512, 512);
  k_gemm<<<dim3(256, 8), 256, 0, stream>>>(hglob, WihH, nullptr, XWXh, 8192, 2048, 512);
  k_transp<<<256, 256, 0, stream>>>(hglob, hT);

  k_decoder<<<32, 512, 0, stream>>>(Whb, hT, Wf, XWXh, lbv, Ain, aouts, barD);
  k_tag<<<512, 256, 0, stream>>>(aouts, WtagP, btagf, dflag, d_out);
}

// Round 11
// 22585.519 us; speedup vs baseline: 1.2825x; 1.2825x over previous
//
#include <hip/hip_runtime.h>
#include <cstdint>
#include <cstddef>

using u16 = unsigned short;
using u32 = unsigned int;

typedef __attribute__((ext_vector_type(8))) __bf16 bf16x8;
typedef __attribute__((ext_vector_type(4))) float f32x4;
typedef __attribute__((ext_vector_type(4))) u32 u32x4;

__device__ __forceinline__ float bf2f(u16 u){
  union { u32 i; float f; } v; v.i = ((u32)u) << 16; return v.f;
}
__device__ __forceinline__ u16 f2bf(float f){
  union { float f; u32 i; } v; v.f = f;
  return (u16)((v.i + 0x7FFFu + ((v.i >> 16) & 1u)) >> 16);
}
__device__ __forceinline__ float sigm(float x){ return 1.0f / (1.0f + __expf(-x)); }
__device__ __forceinline__ f32x4 mfma16(bf16x8 a, bf16x8 b, f32x4 c){
  return __builtin_amdgcn_mfma_f32_16x16x32_bf16(a, b, c, 0, 0, 0);
}
__device__ __forceinline__ float ldin(const void* p, size_t i, bool f){
  return f ? ((const float*)p)[i] : bf2f(((const u16*)p)[i]);
}

// ---- coherence-point (MALL) access primitives: bypass L1/L2 ----
__device__ __forceinline__ u32x4 ldx4_cg(const u16* p){
  u32x4 r;
  asm volatile("global_load_dwordx4 %0, %1, off sc0 sc1" : "=v"(r) : "v"(p) : "memory");
  return r;
}
__device__ __forceinline__ void stx4_cg(u16* p, u32x4 v){
  asm volatile("global_store_dwordx4 %0, %1, off sc0 sc1" :: "v"(p), "v"(v) : "memory");
}
__device__ __forceinline__ void st16_cg(u16* p, u32 v){
  asm volatile("global_store_short %0, %1, off sc0 sc1" :: "v"(p), "v"(v) : "memory");
}
__device__ __forceinline__ void wait_vm0(){ asm volatile("s_waitcnt vmcnt(0)" ::: "memory"); }

// raw workgroup barrier: LDS visibility only, NO vmem drain
__device__ __forceinline__ void lbar(){
  asm volatile("s_waitcnt lgkmcnt(0)" ::: "memory");
  __builtin_amdgcn_sched_barrier(0);
  __builtin_amdgcn_s_barrier();
  __builtin_amdgcn_sched_barrier(0);
}

__device__ __forceinline__ void bar_arrive(u32* bar){
  __hip_atomic_fetch_add(bar, 1u, __ATOMIC_RELAXED, __HIP_MEMORY_SCOPE_AGENT);
}
__device__ __forceinline__ void bar_spin(u32* bar, u32 tgt){
  while (__hip_atomic_load(bar, __ATOMIC_RELAXED, __HIP_MEMORY_SCOPE_AGENT) < tgt)
    __builtin_amdgcn_s_sleep(1);
}

// ---------------- dtype detection ----------------
__global__ __launch_bounds__(256) void k_detect(const u32* __restrict__ embw, u32* __restrict__ dflag){
  int tid = threadIdx.x;
  u32 cnt = 0;
  for (int t = 0; t < 32; ++t){
    u32 w = embw[t*256 + tid];
    u32 e = (w >> 7) & 0xFFu;
    cnt += (e >= 0xC0u) ? 1u : 0u;
  }
  atomicAdd(dflag, cnt);
}

// ---------------- pack (weights -> bf16/f32 in ws) ----------------

__global__ __launch_bounds__(256) void k_pack(
  const void* eWihF, const void* eWihB, const void* ebF, const void* ebB,
  const void* dWih, const void* dWhh, const void* db, const void* Wtag,
  const void* eWhhF, const void* eWhhB, const void* Watt, const void* btag,
  const u32* __restrict__ dflag,
  u16* __restrict__ WihCat, float* __restrict__ bcat, u16* __restrict__ WihH,
  u16* __restrict__ Wf, float* __restrict__ lbv, u16* __restrict__ WtagP,
  u16* __restrict__ WhhFb, u16* __restrict__ WhhBb, u16* __restrict__ Wattb,
  float* __restrict__ btagf)
{
  bool isf = (*dflag > 64u);
  long i = (long)blockIdx.x * 256 + threadIdx.x;
  if (i < 655360){                       // WihCat [2048][320] (K padded 300->320)
    long n = i / 320, e = i - n*320;
    WihCat[i] = (e < 300)
      ? f2bf(ldin(n < 1024 ? eWihF : eWihB, (size_t)(n & 1023)*300 + e, isf)) : (u16)0;
    return;
  }
  i -= 655360;
  if (i < 2048){ bcat[i] = ldin(i < 1024 ? ebF : ebB, (size_t)(i & 1023), isf); return; }
  i -= 2048;
  if (i < 1048576){                      // WihH [2048][512] = dec_Wih[:,512:1024]
    long n = i >> 9, k = i & 511;
    WihH[i] = f2bf(ldin(dWih, (size_t)n*1028 + 512 + k, isf));
    return;
  }
  i -= 1048576;
  if (i < 2097152){                      // Wf: gate weights in MFMA A-fragment layout
    long e  = i & 7;
    long ln = (i >> 3) & 63;
    long kt = (i >> 9) & 31;
    long rt = (i >> 14) & 3;
    long wgi = i >> 16;
    long n = rt*512 + wgi*16 + (ln & 15);
    long k = kt*32 + (ln >> 4)*8 + e;
    Wf[i] = f2bf((k < 512) ? ldin(dWih, (size_t)n*1028 + k, isf)
                           : ldin(dWhh, (size_t)n*512 + (k - 512), isf));
    return;
  }
  i -= 2097152;
  if (i < 8192){                         // lb [4][2048] = dec_b + onehot col
    long l = i >> 11, n = i & 2047;
    lbv[i] = ldin(db, n, isf) + ldin(dWih, (size_t)n*1028 + 1024 + l, isf);
    return;
  }
  i -= 8192;
  if (i < 8192){                         // WtagP [16][512] padded
    long n = i >> 9, k = i & 511;
    WtagP[i] = (n < 9) ? f2bf(ldin(Wtag, (size_t)n*512 + k, isf)) : (u16)0;
    return;
  }
  i -= 8192;
  if (i < 262144){ WhhFb[i] = f2bf(ldin(eWhhF, i, isf)); return; }
  i -= 262144;
  if (i < 262144){ WhhBb[i] = f2bf(ldin(eWhhB, i, isf)); return; }
  i -= 262144;
  if (i < 262144){ Wattb[i] = f2bf(ldin(Watt, i, isf)); return; }
  i -= 262144;
  if (i < 16){ btagf[i] = (i < 9) ? ldin(btag, i, isf) : 0.f; return; }
}

__global__ __launch_bounds__(256) void k_gather(
  const int* __restrict__ seqs, const void* __restrict__ emb,
  const u32* __restrict__ dflag, u16* __restrict__ X)
{
  bool isf = (*dflag > 64u);
  int idx = blockIdx.x * 256 + threadIdx.x;
  if (idx >= 8192*320) return;
  int row = idx / 320, e = idx - row*320;
  int s = row >> 5, b = row & 31;
  int tok = seqs[b*256 + s];
  X[idx] = (e < 300) ? f2bf(ldin(emb, (size_t)tok*300 + e, isf)) : (u16)0;
}

// ---------------- generic bf16 GEMM: C[M,N] = A[M,K] @ B[N,K]^T (+bias) ----------------

__global__ __launch_bounds__(256) void k_gemm(
  const u16* __restrict__ A, const u16* __restrict__ B, const float* __restrict__ bias,
  u16* __restrict__ C, int M, int N, int K)
{
  int mb = blockIdx.x * 32;
  int wave = threadIdx.x >> 6, lane = threadIdx.x & 63;
  int nb = blockIdx.y * 256 + wave * 64;
  int rlo = lane & 15, klane = (lane >> 4) * 8;
  f32x4 acc[2][4];
  #pragma unroll
  for (int i = 0; i < 2; ++i)
    #pragma unroll
    for (int j = 0; j < 4; ++j) acc[i][j] = (f32x4){0,0,0,0};
  for (int kk = 0; kk < K; kk += 32){
    bf16x8 a0 = *(const bf16x8*)(A + (size_t)(mb + rlo)*K + kk + klane);
    bf16x8 a1 = *(const bf16x8*)(A + (size_t)(mb + 16 + rlo)*K + kk + klane);
    #pragma unroll
    for (int nt = 0; nt < 4; ++nt){
      bf16x8 bv = *(const bf16x8*)(B + (size_t)(nb + nt*16 + rlo)*K + kk + klane);
      acc[0][nt] = mfma16(a0, bv, acc[0][nt]);
      acc[1][nt] = mfma16(a1, bv, acc[1][nt]);
    }
  }
  int rbase = (lane >> 4) * 4;
  #pragma unroll
  for (int mt = 0; mt < 2; ++mt)
    #pragma unroll
    for (int nt = 0; nt < 4; ++nt){
      int col = nb + nt*16 + rlo;
      float badd = bias ? bias[col] : 0.0f;
      #pragma unroll
      for (int r = 0; r < 4; ++r){
        int row = mb + mt*16 + rbase + r;
        C[(size_t)row*N + col] = f2bf(acc[mt][nt][r] + badd);
      }
    }
}

// ---------------- transpose h -> hT[b][d][j] ----------------

__global__ __launch_bounds__(256) void k_transp(const u16* __restrict__ hglob, u16* __restrict__ hT)
{
  __shared__ u16 tile_t[64][264];
  int b = blockIdx.x >> 3, d0 = (blockIdx.x & 7) * 64;
  int t = threadIdx.x;
  for (int rr = 0; rr < 16; ++rr){
    int c = rr*256 + t;
    int j = c >> 4, dq = (c & 15) * 4;
    ushort4 ld = *(const ushort4*)(hglob + ((size_t)(j*32 + b)*512 + d0 + dq));
    tile_t[dq + 0][j] = ld.x;
    tile_t[dq + 1][j] = ld.y;
    tile_t[dq + 2][j] = ld.z;
    tile_t[dq + 3][j] = ld.w;
  }
  __syncthreads();
  for (int rr = 0; rr < 8; ++rr){
    int c = rr*256 + t;
    int d = c >> 5, jq = (c & 31) * 8;
    *(uint4*)(hT + ((size_t)(b*512 + d0 + d)*256 + jq)) = *(const uint4*)&tile_t[d][jq];
  }
}

// ---------------- encoder: persistent, 32 WGs (16 per direction) ----------------

__global__ __launch_bounds__(256, 1) void k_encoder(
  const u16* __restrict__ XW, const u16* __restrict__ WhhF, const u16* __restrict__ WhhB,
  u16* __restrict__ hglob, u16* __restrict__ hstate, u32* ctrlE)
{
  int wg = blockIdx.x;
  int d = wg >> 4, w = wg & 15;
  const u16* Whh = d ? WhhB : WhhF;
  u32* bar = ctrlE + d * 256;          // 1024 B apart
  int tid = threadIdx.x, wave = tid >> 6, lane = tid & 63;
  int cc = lane & 15, q = lane >> 4, klane = q * 8, rbase = q * 4;
  __shared__ __align__(16) u16 hblk[8192];     // [b][256] swizzled
  __shared__ float g_lds[4][32][16];
  __shared__ float c_sh[512];
  c_sh[tid] = 0.f; c_sh[tid + 256] = 0.f;
  __syncthreads();

  for (int t = 0; t < 256; ++t){
    int srow = d ? (255 - t) : t;
    const u16* hr = hstate + (size_t)(d*2 + (t & 1)) * 8192;
    u16*       hw = hstate + (size_t)(d*2 + ((t & 1) ^ 1)) * 8192;

    // stage h block (32 x 256) into LDS
    {
      int c0 = tid, c1 = tid + 256, c2 = tid + 512, c3 = tid + 768;
      u32x4 v0 = ldx4_cg(hr + (c0 >> 5)*256 + (c0 & 31)*8);
      u32x4 v1 = ldx4_cg(hr + (c1 >> 5)*256 + (c1 & 31)*8);
      u32x4 v2 = ldx4_cg(hr + (c2 >> 5)*256 + (c2 & 31)*8);
      u32x4 v3 = ldx4_cg(hr + (c3 >> 5)*256 + (c3 & 31)*8);
      wait_vm0();
      *(u32x4*)(hblk + (c0 >> 5)*256 + (((c0 & 31) ^ ((c0 >> 5) & 7)))*8) = v0;
      *(u32x4*)(hblk + (c1 >> 5)*256 + (((c1 & 31) ^ ((c1 >> 5) & 7)))*8) = v1;
      *(u32x4*)(hblk + (c2 >> 5)*256 + (((c2 & 31) ^ ((c2 >> 5) & 7)))*8) = v2;
      *(u32x4*)(hblk + (c3 >> 5)*256 + (((c3 & 31) ^ ((c3 >> 5) & 7)))*8) = v3;
    }
    __syncthreads();

    // h @ Whh^T for this WG's 16 cols x 4 gates
    {
      int ncol = wave*256 + w*16 + cc;
      const u16* Brow = Whh + (size_t)ncol*256;
      f32x4 acc0 = {0,0,0,0}, acc1 = {0,0,0,0};
      #pragma unroll
      for (int kt = 0; kt < 8; ++kt){
        bf16x8 bv = *(const bf16x8*)(Brow + kt*32 + klane);
        bf16x8 a0 = *(const bf16x8*)(hblk + cc*256 + ((kt*4 + q) ^ (cc & 7))*8);
        bf16x8 a1 = *(const bf16x8*)(hblk + (cc + 16)*256 + ((kt*4 + q) ^ (cc & 7))*8);
        acc0 = mfma16(a0, bv, acc0);
        acc1 = mfma16(a1, bv, acc1);
      }
      #pragma unroll
      for (int r = 0; r < 4; ++r){
        g_lds[wave][rbase + r][cc]      = acc0[r];
        g_lds[wave][16 + rbase + r][cc] = acc1[r];
      }
    }
    __syncthreads();

    // pointwise
    for (int e = tid; e < 512; e += 256){
      int b_ = e >> 4, jc = e & 15;
      int j = w*16 + jc;
      float pre[4];
      #pragma unroll
      for (int g2 = 0; g2 < 4; ++g2)
        pre[g2] = g_lds[g2][b_][jc] + bf2f(XW[(size_t)(srow*32 + b_)*2048 + d*1024 + g2*256 + j]);
      float iv = sigm(pre[0]), fv = sigm(pre[1]);
      float gv = tanhf(pre[2]), ov = sigm(pre[3]);
      float cv = fv * c_sh[e] + iv * gv;
      c_sh[e] = cv;
      u16 hb = f2bf(ov * tanhf(cv));
      st16_cg(hw + b_*256 + j, (u32)hb);
      __builtin_nontemporal_store(hb, hglob + (size_t)(srow*32 + b_)*512 + d*256 + j);
    }
    wait_vm0();
    __syncthreads();
    if (tid == 0){
      bar_arrive(bar);
      bar_spin(bar, (u32)(t + 1) * 16u);
    }
    __syncthreads();
  }
}

// ---------------- decoder: persistent, 32 WGs x 512 threads ----------------
// R6 dataflow; sync reworked: raw s_barrier (no vmem drains), wave-0-only coalesced
// MALL stores for ctx/s (per-wave vmcnt ack), aouts stores never waited in-loop.

__global__ __launch_bounds__(512, 1) void k_decoder(
  const u16* __restrict__ Whb, const u16* __restrict__ hT,
  const u16* __restrict__ Wf, const u16* __restrict__ Xh, const float* __restrict__ lbv,
  u16* __restrict__ Ain,          // [2][32][1024] bf16: [b][0:512)=ctx, [512:1024)=s
  u16* __restrict__ aouts,        // [32768][512] bf16
  u32* bar1, u32* bar2)
{
  extern __shared__ __align__(16) u16 ablk[];   // [32][1024], 16B-chunk XOR-swizzled (64KB)
  __shared__ float score_lds[256];
  __shared__ __align__(16) u16 att_bf[256];
  __shared__ __align__(16) u16 ctx_pack[512];
  __shared__ __align__(16) u16 spack[512];
  __shared__ float gbuf[4][16][33];
  __shared__ float c_lds[512];
  const int wg = blockIdx.x, tid = threadIdx.x;
  const int wave = tid >> 6, lane = tid & 63;
  const int q = lane >> 4, cc = lane & 15;
  c_lds[tid] = 0.0f;

  // pin Wh_b A-fragments in VGPRs: wave holds score rows [wave*32, wave*32+32)
  bf16x8 wh[2][16];
  #pragma unroll
  for (int rt = 0; rt < 2; ++rt)
    #pragma unroll
    for (int kt = 0; kt < 16; ++kt){
      int row = wave*32 + rt*16 + cc;
      wh[rt][kt] = *(const bf16x8*)(Whb + ((size_t)(row*32 + wg))*512 + kt*32 + q*8);
    }
  const int grt = wave >> 1, gct = wave & 1;    // gate tile (gate, batch-half) per wave
  const int bcol = gct*16 + cc;
  const u16* WfW = Wf + (size_t)wg*65536;
  const int pb_ = tid >> 4, pdd = tid & 15;     // pointwise role
  const int pgj = wg*16 + pdd;
  float lb[4];
  __syncthreads();

  for (int iter = 0; iter < 1024; ++iter){
    const int l = iter >> 8, t = iter & 255;
    const u32 e = (u32)(iter + 1);
    u16* AinC = Ain + (iter & 1)*32768;
    u16* AinN = Ain + ((iter & 1) ^ 1)*32768;

    // 1. stage s-block (32 x 512) from MALL -> ablk chunks [64,128)
    {
      int c0 = tid, c1 = tid + 512, c2 = tid + 1024, c3 = tid + 1536;
      u32x4 v0 = ldx4_cg(AinC + (c0 >> 6)*1024 + 512 + (c0 & 63)*8);
      u32x4 v1 = ldx4_cg(AinC + (c1 >> 6)*1024 + 512 + (c1 & 63)*8);
      u32x4 v2 = ldx4_cg(AinC + (c2 >> 6)*1024 + 512 + (c2 & 63)*8);
      u32x4 v3 = ldx4_cg(AinC + (c3 >> 6)*1024 + 512 + (c3 & 63)*8);
      wait_vm0();
      *(u32x4*)(ablk + (c0 >> 6)*1024 + (64 + ((c0 & 63) ^ ((c0 >> 6) & 7)))*8) = v0;
      *(u32x4*)(ablk + (c1 >> 6)*1024 + (64 + ((c1 & 63) ^ ((c1 >> 6) & 7)))*8) = v1;
      *(u32x4*)(ablk + (c2 >> 6)*1024 + (64 + ((c2 & 63) ^ ((c2 >> 6) & 7)))*8) = v2;
      *(u32x4*)(ablk + (c3 >> 6)*1024 + (64 + ((c3 & 63) ^ ((c3 >> 6) & 7)))*8) = v3;
    }
    lbar();

    // 2. prefetch pointwise operands (cached loads; float across raw barriers)
    if ((iter & 255) == 0){
      #pragma unroll
      for (int g = 0; g < 4; ++g) lb[g] = lbv[l*2048 + g*512 + pgj];
    }
    float xh[4];
    #pragma unroll
    for (int g = 0; g < 4; ++g) xh[g] = bf2f(Xh[(size_t)(t*32 + pb_)*2048 + g*512 + pgj]);

    // 3. scores: MFMA(Wh-VGPR, own-s broadcast)
    {
      f32x4 sa0 = {0,0,0,0}, sa1 = {0,0,0,0};
      #pragma unroll
      for (int kt = 0; kt < 16; ++kt){
        bf16x8 sv = *(const bf16x8*)(ablk + wg*1024 + ((64 + kt*4 + q) ^ (wg & 7))*8);
        sa0 = mfma16(wh[0][kt], sv, sa0);
        sa1 = mfma16(wh[1][kt], sv, sa1);
      }
      if (cc == 0){
        #pragma unroll
        for (int r = 0; r < 4; ++r){
          score_lds[wave*32      + q*4 + r] = sa0[r];
          score_lds[wave*32 + 16 + q*4 + r] = sa1[r];
        }
      }
    }
    lbar();

    // 4. softmax (wave 0, 4 scores/lane)
    if (wave == 0){
      float x0 = score_lds[lane*4+0], x1 = score_lds[lane*4+1];
      float x2 = score_lds[lane*4+2], x3 = score_lds[lane*4+3];
      float m = fmaxf(fmaxf(x0,x1), fmaxf(x2,x3));
      #pragma unroll
      for (int off = 32; off >= 1; off >>= 1) m = fmaxf(m, __shfl_xor(m, off));
      float e0 = __expf(x0-m), e1 = __expf(x1-m), e2 = __expf(x2-m), e3 = __expf(x3-m);
      float s = e0+e1+e2+e3;
      #pragma unroll
      for (int off = 32; off >= 1; off >>= 1) s += __shfl_xor(s, off);
      float inv = 1.0f / s;
      att_bf[lane*4+0] = f2bf(e0*inv);
      att_bf[lane*4+1] = f2bf(e1*inv);
      att_bf[lane*4+2] = f2bf(e2*inv);
      att_bf[lane*4+3] = f2bf(e3*inv);
    }
    lbar();

    // 5. ctx: MFMA(att row-0, hT B-frags). wave owns dims [wave*64, wave*64+64)
    {
      f32x4 ca0 = {0,0,0,0}, ca1 = {0,0,0,0}, ca2 = {0,0,0,0}, ca3 = {0,0,0,0};
      #pragma unroll
      for (int jt = 0; jt < 8; ++jt){
        uint4 au = {0,0,0,0};
        if (cc == 0) au = *(const uint4*)(att_bf + jt*32 + q*8);
        bf16x8 af = *(bf16x8*)&au;
        const u16* hb = hT + ((size_t)(wg*512 + wave*64 + cc))*256 + jt*32 + q*8;
        ca0 = mfma16(af, *(const bf16x8*)(hb +  0*256), ca0);
        ca1 = mfma16(af, *(const bf16x8*)(hb + 16*256), ca1);
        ca2 = mfma16(af, *(const bf16x8*)(hb + 32*256), ca2);
        ca3 = mfma16(af, *(const bf16x8*)(hb + 48*256), ca3);
      }
      if (q == 0){
        ctx_pack[wave*64 +  0 + cc] = f2bf(ca0[0]);
        ctx_pack[wave*64 + 16 + cc] = f2bf(ca1[0]);
        ctx_pack[wave*64 + 32 + cc] = f2bf(ca2[0]);
        ctx_pack[wave*64 + 48 + cc] = f2bf(ca3[0]);
      }
    }
    lbar();

    // 6. wave0: coalesced ctx store + per-wave ack + arrive; all: gate s-half; tid0: spin
    if (wave == 0){
      u32x4 v = *(const u32x4*)(ctx_pack + lane*8);
      stx4_cg(AinC + (size_t)wg*1024 + lane*8, v);
      wait_vm0();
      if (lane == 0) bar_arrive(bar2);
    }
    f32x4 ga = {0,0,0,0};
    #pragma unroll
    for (int kt = 16; kt < 32; ++kt){
      bf16x8 wa = *(const bf16x8*)(WfW + ((grt*32 + kt)*64 + lane)*8);
      bf16x8 av = *(const bf16x8*)(ablk + bcol*1024 + ((kt*4 + q) ^ (bcol & 7))*8);
      ga = mfma16(wa, av, ga);
    }
    if (tid == 0) bar_spin(bar2, 32u*e);
    lbar();

    // 7. stage ctx-block (32 x 512) from MALL -> ablk chunks [0,64)
    {
      int c0 = tid, c1 = tid + 512, c2 = tid + 1024, c3 = tid + 1536;
      u32x4 v0 = ldx4_cg(AinC + (c0 >> 6)*1024 + (c0 & 63)*8);
      u32x4 v1 = ldx4_cg(AinC + (c1 >> 6)*1024 + (c1 & 63)*8);
      u32x4 v2 = ldx4_cg(AinC + (c2 >> 6)*1024 + (c2 & 63)*8);
      u32x4 v3 = ldx4_cg(AinC + (c3 >> 6)*1024 + (c3 & 63)*8);
      wait_vm0();
      *(u32x4*)(ablk + (c0 >> 6)*1024 + (((c0 & 63) ^ ((c0 >> 6) & 7)))*8) = v0;
      *(u32x4*)(ablk + (c1 >> 6)*1024 + (((c1 & 63) ^ ((c1 >> 6) & 7)))*8) = v1;
      *(u32x4*)(ablk + (c2 >> 6)*1024 + (((c2 & 63) ^ ((c2 >> 6) & 7)))*8) = v2;
      *(u32x4*)(ablk + (c3 >> 6)*1024 + (((c3 & 63) ^ ((c3 >> 6) & 7)))*8) = v3;
    }
    lbar();

    // 8. gate ctx-half (K 0..511)
    #pragma unroll
    for (int kt = 0; kt < 16; ++kt){
      bf16x8 wa = *(const bf16x8*)(WfW + ((grt*32 + kt)*64 + lane)*8);
      bf16x8 av = *(const bf16x8*)(ablk + bcol*1024 + ((kt*4 + q) ^ (bcol & 7))*8);
      ga = mfma16(wa, av, ga);
    }
    #pragma unroll
    for (int r = 0; r < 4; ++r) gbuf[grt][q*4 + r][bcol] = ga[r];
    lbar();

    // 9. pointwise: thread = (pb_, pdd); this WG owns h-dims [wg*16, wg*16+16)
    {
      float pre[4];
      #pragma unroll
      for (int g = 0; g < 4; ++g)
        pre[g] = gbuf[g][pdd][pb_] + xh[g] + lb[g];
      float iv = sigm(pre[0]), fv = sigm(pre[1]);
      float gv = tanhf(pre[2]), ov = sigm(pre[3]);
      float cv = fv * c_lds[tid] + iv * gv;
      c_lds[tid] = cv;
      spack[pb_*16 + pdd] = f2bf(ov * tanhf(cv));
    }
    lbar();

    // 10. wave0: coalesced s store + ack + arrive; wave1: aouts stores (never waited);
    //     tid0: spin
    if (wave == 0){
      u32x4 v = *(const u32x4*)(spack + lane*8);
      stx4_cg(AinN + (size_t)(lane >> 1)*1024 + 512 + wg*16 + (lane & 1)*8, v);
      wait_vm0();
      if (lane == 0) bar_arrive(bar1);
    } else if (wave == 1){
      u32x4 v = *(const u32x4*)(spack + lane*8);
      stx4_cg(aouts + ((size_t)((l*256 + t)*32) + (lane >> 1))*512 + wg*16 + (lane & 1)*8, v);
    }
    if (tid == 0) bar_spin(bar1, 32u*e);
    lbar();
  }
}

// ---------------- tag projection ----------------

__global__ __launch_bounds__(256) void k_tag(
  const u16* __restrict__ aouts, const u16* __restrict__ WtagP, const float* __restrict__ btagf,
  const u32* __restrict__ dflag, void* __restrict__ out)
{
  bool isf = (*dflag > 64u);
  int wave = threadIdx.x >> 6, lane = threadIdx.x & 63;
  int mb = (blockIdx.x * 4 + wave) * 16;
  int cc = lane & 15, klane = (lane >> 4) * 8;
  f32x4 acc = {0,0,0,0};
  const u16* Arow = aouts + (size_t)(mb + cc)*512;
  const u16* Brow = WtagP + cc*512;
  #pragma unroll
  for (int kk = 0; kk < 512; kk += 32){
    bf16x8 av = *(const bf16x8*)(Arow + kk + klane);
    bf16x8 bv = *(const bf16x8*)(Brow + kk + klane);
    acc = mfma16(av, bv, acc);
  }
  int rbase = (lane >> 4) * 4;
  if (cc < 9){
    float bt = btagf[cc];
    #pragma unroll
    for (int r = 0; r < 4; ++r){
      int row = mb + rbase + r;
      float v = acc[r] + bt;
      if (isf) ((float*)out)[(size_t)row*9 + cc] = v;
      else     ((u16*)out)[(size_t)row*9 + cc] = f2bf(v);
    }
  }
}

// ---------------- host ----------------

extern "C" void kernel_launch(void* const* d_in, const int* in_sizes, int n_in,
                              void* d_out, int out_size, void* d_ws, size_t ws_size,
                              hipStream_t stream)
{
  (void)in_sizes; (void)n_in; (void)out_size;
  if (ws_size < 98625536ull) return;

  const int* seqs = (const int*)d_in[0];

  char* ws = (char*)d_ws;
  u32*    dflag  = (u32*)(ws + 0);
  u32*    barEF  = (u32*)(ws + 1024);       // encoder fwd bar; bwd at +1024
  u32*    barD1  = (u32*)(ws + 3072);       // decoder state bar
  u32*    barD2  = (u32*)(ws + 4096);       // decoder ctx bar
  u16*    Ain    = (u16*)(ws + 8192);       // [2][32][1024] bf16 -> end 139264
  u16*    hstate = (u16*)(ws + 139264);     // [4][32][256] -> end 204800
  // memset end = 204800
  u16*    WihCat = (u16*)(ws + 263168);     // [2048][320]
  float*  bcat   = (float*)(ws + 1573888);  // [2048]
  u16*    WihH   = (u16*)(ws + 1582080);    // [2048][512]
  u16*    Wf     = (u16*)(ws + 3679232);    // [32][4][32][64][8] fragment layout (4MB)
  float*  lbv    = (float*)(ws + 7873536);  // [4][2048]
  u16*    WtagP  = (u16*)(ws + 7906304);    // [16][512]
  u16*    WhhFb  = (u16*)(ws + 7922688);    // [1024][256]
  u16*    WhhBb  = (u16*)(ws + 8446976);    // [1024][256]
  u16*    Wattb  = (u16*)(ws + 8971264);    // [512][512]
  float*  btagf  = (float*)(ws + 9495552);  // [16]
  u16*    X      = (u16*)(ws + 9496576);    // [8192][320]
  u16*    XWXh   = (u16*)(ws + 14739456);   // [8192][2048] XW, later Xh (aliased)
  u16*    aouts  = (u16*)(ws + 48293888);   // [32768][512]; first 8.4MB doubles as hglob pre-decoder
  u16*    hglob  = (u16*)(ws + 48293888);   // alias (dead before decoder writes aouts)
  u16*    hT     = (u16*)(ws + 81848320);   // [32][512][256]
  u16*    Whb    = (u16*)(ws + 90236928);   // [8192][512]

  hipMemsetAsync(d_ws, 0, 204800, stream);

  k_detect<<<1, 256, 0, stream>>>((const u32*)d_in[1], dflag);
  k_pack<<<17993, 256, 0, stream>>>(
      d_in[2], d_in[5], d_in[4], d_in[7], d_in[9], d_in[10], d_in[11], d_in[12],
      d_in[3], d_in[6], d_in[8], d_in[13], dflag,
      WihCat, bcat, WihH, Wf, lbv, WtagP, WhhFb, WhhBb, Wattb, btagf);
  k_gather<<<10240, 256, 0, stream>>>(seqs, d_in[1], dflag, X);
  // XW = X @ [Wih_f; Wih_b]^T + bias
  k_gemm<<<dim3(256, 8), 256, 0, stream>>>(X, WihCat, bcat, XWXh, 8192, 2048, 320);
  k_encoder<<<32, 256, 0, stream>>>(XWXh, WhhFb, WhhBb, hglob, hstate, barEF);
  // Wh = h @ W_att^T ; Xh = h @ Wih_h^T (aliases XW)
  k_gemm<<<dim3(256, 2), 256, 0, stream>>>(hglob, Wattb, nullptr, Whb, 8192, 512, 512);
  k_gemm<<<dim3(256, 8), 256, 0, stream>>>(hglob, WihH, nullptr, XWXh, 8192, 2048, 512);
  k_transp<<<256, 256, 0, stream>>>(hglob, hT);

  k_decoder<<<32, 512, 65536, stream>>>(Whb, hT, Wf, XWXh, lbv, Ain, aouts, barD1, barD2);
  k_tag<<<512, 256, 0, stream>>>(aouts, WtagP, btagf, dflag, d_out);
}